// Round 1
// baseline (178.981 us; speedup 1.0000x reference)
//
#include <hip/hip_runtime.h>
#include <cstdint>
#include <cstddef>

// ---------------------------------------------------------------------------
// LSTM cell, B=8192, D=H=512, fp32 in/out.
//   pre[g] = x @ Wx[g]^T + h @ Wh[g]^T + bx[g] + bh[g]   (g in {f,i,g,o})
//   c_t = sig(f)*c_prev + sig(i)*tanh(g);  h_t = sig(o)*tanh(c_t)
// Strategy: bf16 pack of A=[x|h] (8192x1024) and W-stack (2048x1024), then one
// fused MFMA GEMM (128x128 stacked tile = 128 batch x 32 hidden x 4 gates)
// with the gate nonlinearity + c/h computation fused into the epilogue.
// ---------------------------------------------------------------------------

typedef __attribute__((ext_vector_type(8))) short short8;   // 8 bf16 = 4 VGPRs
typedef __attribute__((ext_vector_type(4))) float floatx4;  // MFMA acc

#define AS1(p) ((const __attribute__((address_space(1))) void*)(p))
#define AS3(p) ((__attribute__((address_space(3))) void*)(p))

__device__ __forceinline__ unsigned short f2bf(float f) {
  union { float f; unsigned u; } v; v.f = f;
  unsigned u = v.u;
  // round-to-nearest-even
  return (unsigned short)((u + 0x7fffu + ((u >> 16) & 1u)) >> 16);
}

// --------------------------- pack A = [x | h] ------------------------------
// A_bf16[b][k] : k<512 -> x[b][k], else h[b][k-512].  8192x1024 bf16.
__global__ void pack_a_kernel(const float* __restrict__ x,
                              const float* __restrict__ h,
                              unsigned short* __restrict__ A) {
  int e4 = blockIdx.x * 256 + threadIdx.x;   // 2,097,152 threads, 4 elems each
  int e = e4 * 4;
  int b = e >> 10;
  int k = e & 1023;
  const float* src = (k < 512) ? (x + b * 512 + k) : (h + b * 512 + (k - 512));
  float4 v = *(const float4*)src;
  ushort4 o;
  o.x = f2bf(v.x); o.y = f2bf(v.y); o.z = f2bf(v.z); o.w = f2bf(v.w);
  *(ushort4*)(A + e) = o;
}

// --------------------------- pack W stack ----------------------------------
// Bmat[n][k], n = gate*512 + hh (gate order f,i,g,o); k<512 -> Wx[g][hh][k],
// else Wh[g][hh][k-512]. Also combined bias[n] = bx[g][hh] + bh[g][hh].
struct WPtrs {
  const float* wx[4]; const float* wh[4];
  const float* bx[4]; const float* bh[4];
};

__global__ void pack_w_kernel(WPtrs P, unsigned short* __restrict__ B,
                              float* __restrict__ bias) {
  int e4 = blockIdx.x * 256 + threadIdx.x;   // 524,288 threads, 4 elems each
  int e = e4 * 4;
  int n = e >> 10;
  int k = e & 1023;
  int g = n >> 9, hh = n & 511;
  const float* src = (k < 512) ? (P.wx[g] + hh * 512 + k)
                               : (P.wh[g] + hh * 512 + (k - 512));
  float4 v = *(const float4*)src;
  ushort4 o;
  o.x = f2bf(v.x); o.y = f2bf(v.y); o.z = f2bf(v.z); o.w = f2bf(v.w);
  *(ushort4*)(B + e) = o;
  if (k == 0) bias[n] = P.bx[g][hh] + P.bh[g][hh];
}

// --------------------------- fused GEMM + LSTM epilogue --------------------
// Grid (64, 16): block = 128 batch rows x (4 gates x 32 hidden).
// K = 1024, BK = 64, 256 threads = 4 waves, each wave 64x64 (4x4 MFMA frags).
__global__ __launch_bounds__(256)
void lstm_gemm_kernel(const unsigned short* __restrict__ A,   // [8192][1024]
                      const unsigned short* __restrict__ B,   // [2048][1024]
                      const float* __restrict__ bias,         // [2048]
                      const float* __restrict__ c_prev,       // [8192][512]
                      float* __restrict__ h_out,              // [8192][512]
                      float* __restrict__ c_out) {            // [8192][512]
  // staging: As 16KB @ [0,16384), Bs 16KB @ [16384,32768)
  // epilogue reuse: float[64][132] = 33792 B
  __shared__ __align__(16) char smem[33792];
  __shared__ float biasS[128];

  const int tid  = threadIdx.x;
  const int lane = tid & 63;
  const int w    = tid >> 6;
  const int quad = lane >> 4;
  const int colA = lane & 15;
  const int m0   = blockIdx.x * 128;
  const int h0   = blockIdx.y * 32;

  if (tid < 128) {
    int g = tid >> 5, hh = tid & 31;
    biasS[tid] = bias[g * 512 + h0 + hh];
  }

  // staging geometry: per call j, thread covers tile-row r = j*32 + (tid>>3),
  // 16B chunk (tid&7). XOR-swizzle the *global* chunk by (row&7) so that
  // ds_read_b128 fragment reads are bank-conflict-free.
  const int srow = tid >> 3;        // 0..31
  const int cl   = tid & 7;         // LDS chunk slot (fixed by HW lane order)
  const int cg   = cl ^ (srow & 7); // swizzled global chunk

  floatx4 acc[4][4];
#pragma unroll
  for (int i = 0; i < 4; ++i)
#pragma unroll
    for (int j = 0; j < 4; ++j) acc[i][j] = (floatx4){0.f, 0.f, 0.f, 0.f};

  const int wm = (w >> 1) * 64;   // wave M offset in tile
  const int wn = (w & 1) * 64;    // wave N' offset in tile (N' = gate*32+h)

  const char* Ag = (const char*)A;
  const char* Bg = (const char*)B;

  for (int kt = 0; kt < 16; ++kt) {
    __syncthreads();               // previous iter's LDS reads complete
    const int kb = kt * 128;       // byte offset into 2048-B rows
#pragma unroll
    for (int j = 0; j < 4; ++j) {
      int r = j * 32 + srow;       // tile row 0..127
      // A tile rows m0 + r
      __builtin_amdgcn_global_load_lds(
          AS1(Ag + (size_t)(m0 + r) * 2048 + kb + cg * 16),
          AS3(smem + r * 128 + cl * 16), 16, 0, 0);
      // B tile: call j stages gate j's 32 rows (r>>5 == j)
      __builtin_amdgcn_global_load_lds(
          AS1(Bg + (size_t)(j * 512 + h0 + srow) * 2048 + kb + cg * 16),
          AS3(smem + 16384 + r * 128 + cl * 16), 16, 0, 0);
    }
    __syncthreads();               // drains vmcnt(0) for global_load_lds

#pragma unroll
    for (int kk = 0; kk < 2; ++kk) {
      // fragment row's swizzle factor: row&7 == colA&7 == lane&7
      const int off = ((kk * 4 + quad) ^ (lane & 7)) * 16;
      short8 af[4], bfr[4];
#pragma unroll
      for (int mi = 0; mi < 4; ++mi)
        af[mi] = *(const short8*)(smem + (wm + mi * 16 + colA) * 128 + off);
#pragma unroll
      for (int ni = 0; ni < 4; ++ni)
        bfr[ni] = *(const short8*)(smem + 16384 + (wn + ni * 16 + colA) * 128 + off);
#pragma unroll
      for (int mi = 0; mi < 4; ++mi)
#pragma unroll
        for (int ni = 0; ni < 4; ++ni)
          acc[mi][ni] = __builtin_amdgcn_mfma_f32_16x16x32_bf16(
              af[mi], bfr[ni], acc[mi][ni], 0, 0, 0);
    }
  }

  // ------------------- fused epilogue (2 rounds of 64 M-rows) --------------
  __syncthreads();
  float* ep = (float*)smem;        // [64][132] padded
#pragma unroll
  for (int rd = 0; rd < 2; ++rd) {
    if ((w >> 1) == rd) {
      // C/D layout: row = quad*4 + rr, col = lane&15
#pragma unroll
      for (int mi = 0; mi < 4; ++mi)
#pragma unroll
        for (int ni = 0; ni < 4; ++ni) {
          int rr0 = mi * 16 + quad * 4;
          int cc  = wn + ni * 16 + colA;
#pragma unroll
          for (int rr = 0; rr < 4; ++rr)
            ep[(rr0 + rr) * 132 + cc] = acc[mi][ni][rr];
        }
    }
    __syncthreads();
#pragma unroll
    for (int j = 0; j < 8; ++j) {
      int idx  = j * 256 + tid;    // 0..2047
      int mloc = idx >> 5;
      int hh   = idx & 31;
      float pf = ep[mloc * 132 +      hh] + biasS[hh];
      float pi = ep[mloc * 132 + 32 + hh] + biasS[32 + hh];
      float pg = ep[mloc * 132 + 64 + hh] + biasS[64 + hh];
      float po = ep[mloc * 132 + 96 + hh] + biasS[96 + hh];
      float fg = 1.f / (1.f + __expf(-pf));
      float ig = 1.f / (1.f + __expf(-pi));
      float gg = 1.f - 2.f / (1.f + __expf(2.f * pg));
      float og = 1.f / (1.f + __expf(-po));
      int m  = m0 + rd * 64 + mloc;
      int hg = h0 + hh;
      float cp = c_prev[m * 512 + hg];
      float cv = fg * cp + ig * gg;
      float th = 1.f - 2.f / (1.f + __expf(2.f * cv));
      h_out[m * 512 + hg] = og * th;
      c_out[m * 512 + hg] = cv;
    }
    __syncthreads();
  }
}

// ---------------------------------------------------------------------------
extern "C" void kernel_launch(void* const* d_in, const int* in_sizes, int n_in,
                              void* d_out, int out_size, void* d_ws, size_t ws_size,
                              hipStream_t stream) {
  const float* x = (const float*)d_in[0];
  const float* h = (const float*)d_in[1];
  const float* c = (const float*)d_in[2];

  // workspace layout: A_bf16 (16 MiB) | B_bf16 (4 MiB) | bias (8 KiB)
  char* ws = (char*)d_ws;
  unsigned short* Abf = (unsigned short*)ws;
  unsigned short* Bbf = (unsigned short*)(ws + (size_t)16777216);
  float* bias = (float*)(ws + (size_t)16777216 + 4194304);

  float* hout = (float*)d_out;
  float* cout = hout + (size_t)8192 * 512;

  pack_a_kernel<<<8192, 256, 0, stream>>>(x, h, Abf);

  WPtrs P;
  // gate order in stacked B: 0=f, 1=i, 2=g(cell), 3=o
  P.wx[0] = (const float*)d_in[3];  P.bx[0] = (const float*)d_in[4];
  P.wh[0] = (const float*)d_in[5];  P.bh[0] = (const float*)d_in[6];
  P.wx[1] = (const float*)d_in[7];  P.bx[1] = (const float*)d_in[8];
  P.wh[1] = (const float*)d_in[9];  P.bh[1] = (const float*)d_in[10];
  P.wx[2] = (const float*)d_in[11]; P.bx[2] = (const float*)d_in[12];
  P.wh[2] = (const float*)d_in[13]; P.bh[2] = (const float*)d_in[14];
  P.wx[3] = (const float*)d_in[15]; P.bx[3] = (const float*)d_in[16];
  P.wh[3] = (const float*)d_in[17]; P.bh[3] = (const float*)d_in[18];
  pack_w_kernel<<<2048, 256, 0, stream>>>(P, Bbf, bias);

  dim3 grid(64, 16);
  lstm_gemm_kernel<<<grid, 256, 0, stream>>>(Abf, Bbf, bias, c, hout, cout);
}

// Round 2
// 173.478 us; speedup vs baseline: 1.0317x; 1.0317x over previous
//
#include <hip/hip_runtime.h>
#include <cstdint>
#include <cstddef>

// ---------------------------------------------------------------------------
// LSTM cell, B=8192, D=H=512, fp32 in/out.
// pre = [x|h] @ Wstack^T + bias ; gates -> c_t, h_t fused in GEMM epilogue.
// Round 2: (a) single pack kernel for A/B/bias, (b) GEMM with 512 threads
// (8 waves of 32x64) for 2x schedulable waves/CU to hide the barrier drain.
// ---------------------------------------------------------------------------

typedef __attribute__((ext_vector_type(8))) short short8;   // 8 bf16 = 4 VGPRs
typedef __attribute__((ext_vector_type(4))) float floatx4;  // MFMA acc

#define AS1(p) ((const __attribute__((address_space(1))) void*)(p))
#define AS3(p) ((__attribute__((address_space(3))) void*)(p))

__device__ __forceinline__ unsigned short f2bf(float f) {
  union { float f; unsigned u; } v; v.f = f;
  unsigned u = v.u;
  return (unsigned short)((u + 0x7fffu + ((u >> 16) & 1u)) >> 16);  // RNE
}

// --------------------------- pack everything -------------------------------
// blocks [0,8192):   A[b][k] = k<512 ? x[b][k] : h[b][k-512]      (8192x1024)
// blocks [8192,10240): B[n][k], n=gate*512+hh (f,i,g,o), k<512 -> Wx else Wh
//                      plus bias[n] = bx+bh at k==0.
struct PackArgs {
  const float* x; const float* h;
  const float* wx[4]; const float* wh[4];
  const float* bx[4]; const float* bh[4];
  unsigned short* A; unsigned short* B; float* bias;
};

__global__ __launch_bounds__(256) void pack_all_kernel(PackArgs P) {
  const int bid = blockIdx.x;
  if (bid < 8192) {
    int e = (bid * 256 + threadIdx.x) * 4;
    int b = e >> 10, k = e & 1023;
    const float* src = (k < 512) ? (P.x + b * 512 + k)
                                 : (P.h + b * 512 + (k - 512));
    float4 v = *(const float4*)src;
    ushort4 o;
    o.x = f2bf(v.x); o.y = f2bf(v.y); o.z = f2bf(v.z); o.w = f2bf(v.w);
    *(ushort4*)(P.A + e) = o;
  } else {
    int e = ((bid - 8192) * 256 + threadIdx.x) * 4;
    int n = e >> 10, k = e & 1023;
    int g = n >> 9, hh = n & 511;
    const float* src = (k < 512) ? (P.wx[g] + hh * 512 + k)
                                 : (P.wh[g] + hh * 512 + (k - 512));
    float4 v = *(const float4*)src;
    ushort4 o;
    o.x = f2bf(v.x); o.y = f2bf(v.y); o.z = f2bf(v.z); o.w = f2bf(v.w);
    *(ushort4*)(P.B + e) = o;
    if (k == 0) P.bias[n] = P.bx[g][hh] + P.bh[g][hh];
  }
}

// --------------------------- fused GEMM + LSTM epilogue --------------------
// Grid (64,16): tile = 128 batch x (4 gates x 32 hidden). K=1024, BK=64.
// 512 threads = 8 waves; wave tile 32x64 (2x4 frags of 16x16x32 bf16).
__global__ __launch_bounds__(512, 6)
void lstm_gemm_kernel(const unsigned short* __restrict__ A,   // [8192][1024]
                      const unsigned short* __restrict__ B,   // [2048][1024]
                      const float* __restrict__ bias,         // [2048]
                      const float* __restrict__ c_prev,       // [8192][512]
                      float* __restrict__ h_out,              // [8192][512]
                      float* __restrict__ c_out) {            // [8192][512]
  // staging: As 16KB @ [0,16384), Bs 16KB @ [16384,32768)
  // epilogue overlay: float[64][132] = 33792 B; bias at [33792, 34304)
  __shared__ __align__(16) char smem[34304];
  float* biasS = (float*)(smem + 33792);

  const int tid  = threadIdx.x;
  const int lane = tid & 63;
  const int w    = tid >> 6;        // wave 0..7
  const int quad = lane >> 4;
  const int colA = lane & 15;
  const int m0   = blockIdx.x * 128;
  const int h0   = blockIdx.y * 32;

  if (tid < 128) {
    int g = tid >> 5, hh = tid & 31;
    biasS[tid] = bias[g * 512 + h0 + hh];
  }

  // staging: thread covers tile-row r = j*64 + (tid>>3), 16B chunk (tid&7);
  // global chunk XOR-swizzled by row&7 so ds_read_b128 frags are conflict-free
  const int srow = tid >> 3;        // 0..63
  const int cl   = tid & 7;
  const int cg   = cl ^ (srow & 7);

  floatx4 acc[2][4];
#pragma unroll
  for (int i = 0; i < 2; ++i)
#pragma unroll
    for (int j = 0; j < 4; ++j) acc[i][j] = (floatx4){0.f, 0.f, 0.f, 0.f};

  const int wm = (w >> 1) * 32;     // wave M offset in tile (0,32,64,96)
  const int wn = (w & 1) * 64;      // wave N' offset (N' = gate*32+h)

  const char* Ag = (const char*)A;
  const char* Bg = (const char*)B;

  for (int kt = 0; kt < 16; ++kt) {
    __syncthreads();                // prior LDS reads done
    const int kb = kt * 128;        // byte offset into 2048-B rows
#pragma unroll
    for (int j = 0; j < 2; ++j) {
      int r = j * 64 + srow;        // tile row 0..127
      __builtin_amdgcn_global_load_lds(
          AS1(Ag + (size_t)(m0 + r) * 2048 + kb + cg * 16),
          AS3(smem + r * 128 + cl * 16), 16, 0, 0);
      int grow = (r >> 5) * 512 + h0 + (r & 31);   // gate-major B row
      __builtin_amdgcn_global_load_lds(
          AS1(Bg + (size_t)grow * 2048 + kb + cg * 16),
          AS3(smem + 16384 + r * 128 + cl * 16), 16, 0, 0);
    }
    __syncthreads();                // drains vmcnt(0)

#pragma unroll
    for (int kk = 0; kk < 2; ++kk) {
      const int off = ((kk * 4 + quad) ^ (lane & 7)) * 16;
      short8 af[2], bfr[4];
#pragma unroll
      for (int mi = 0; mi < 2; ++mi)
        af[mi] = *(const short8*)(smem + (wm + mi * 16 + colA) * 128 + off);
#pragma unroll
      for (int ni = 0; ni < 4; ++ni)
        bfr[ni] = *(const short8*)(smem + 16384 + (wn + ni * 16 + colA) * 128 + off);
#pragma unroll
      for (int mi = 0; mi < 2; ++mi)
#pragma unroll
        for (int ni = 0; ni < 4; ++ni)
          acc[mi][ni] = __builtin_amdgcn_mfma_f32_16x16x32_bf16(
              af[mi], bfr[ni], acc[mi][ni], 0, 0, 0);
    }
  }

  // ------------------- fused epilogue (2 rounds of 64 M-rows) --------------
  __syncthreads();
  float* ep = (float*)smem;         // [64][132] padded
#pragma unroll
  for (int rd = 0; rd < 2; ++rd) {
    if ((w >> 2) == rd) {           // waves whose wm is in [rd*64, rd*64+64)
      // C/D layout: row = quad*4 + rr, col = lane&15
#pragma unroll
      for (int mi = 0; mi < 2; ++mi)
#pragma unroll
        for (int ni = 0; ni < 4; ++ni) {
          int rr0 = (wm - rd * 64) + mi * 16 + quad * 4;  // 0..63
          int cc  = wn + ni * 16 + colA;
#pragma unroll
          for (int rr = 0; rr < 4; ++rr)
            ep[(rr0 + rr) * 132 + cc] = acc[mi][ni][rr];
        }
    }
    __syncthreads();
#pragma unroll
    for (int j = 0; j < 4; ++j) {
      int idx  = j * 512 + tid;     // 0..2047
      int mloc = idx >> 5;
      int hh   = idx & 31;
      float pf = ep[mloc * 132 +      hh] + biasS[hh];
      float pi = ep[mloc * 132 + 32 + hh] + biasS[32 + hh];
      float pg = ep[mloc * 132 + 64 + hh] + biasS[64 + hh];
      float po = ep[mloc * 132 + 96 + hh] + biasS[96 + hh];
      float fg = 1.f / (1.f + __expf(-pf));
      float ig = 1.f / (1.f + __expf(-pi));
      float gg = 1.f - 2.f / (1.f + __expf(2.f * pg));
      float og = 1.f / (1.f + __expf(-po));
      int m  = m0 + rd * 64 + mloc;
      int hg = h0 + hh;
      float cp = c_prev[m * 512 + hg];
      float cv = fg * cp + ig * gg;
      float th = 1.f - 2.f / (1.f + __expf(2.f * cv));
      h_out[m * 512 + hg] = og * th;
      c_out[m * 512 + hg] = cv;
    }
    __syncthreads();
  }
}

// ---------------------------------------------------------------------------
extern "C" void kernel_launch(void* const* d_in, const int* in_sizes, int n_in,
                              void* d_out, int out_size, void* d_ws, size_t ws_size,
                              hipStream_t stream) {
  // workspace: A_bf16 (16 MiB) | B_bf16 (4 MiB) | bias (8 KiB)
  char* ws = (char*)d_ws;
  unsigned short* Abf = (unsigned short*)ws;
  unsigned short* Bbf = (unsigned short*)(ws + (size_t)16777216);
  float* bias = (float*)(ws + (size_t)16777216 + 4194304);

  float* hout = (float*)d_out;
  float* cout = hout + (size_t)8192 * 512;

  PackArgs P;
  P.x = (const float*)d_in[0];
  P.h = (const float*)d_in[1];
  // gate order in stacked B: 0=f, 1=i, 2=g(cell), 3=o
  P.wx[0] = (const float*)d_in[3];  P.bx[0] = (const float*)d_in[4];
  P.wh[0] = (const float*)d_in[5];  P.bh[0] = (const float*)d_in[6];
  P.wx[1] = (const float*)d_in[7];  P.bx[1] = (const float*)d_in[8];
  P.wh[1] = (const float*)d_in[9];  P.bh[1] = (const float*)d_in[10];
  P.wx[2] = (const float*)d_in[11]; P.bx[2] = (const float*)d_in[12];
  P.wh[2] = (const float*)d_in[13]; P.bh[2] = (const float*)d_in[14];
  P.wx[3] = (const float*)d_in[15]; P.bx[3] = (const float*)d_in[16];
  P.wh[3] = (const float*)d_in[17]; P.bh[3] = (const float*)d_in[18];
  P.A = Abf; P.B = Bbf; P.bias = bias;

  pack_all_kernel<<<10240, 256, 0, stream>>>(P);

  const float* c = (const float*)d_in[2];
  dim3 grid(64, 16);
  lstm_gemm_kernel<<<grid, 512, 0, stream>>>(Abf, Bbf, bias, c, hout, cout);
}

// Round 3
// 167.560 us; speedup vs baseline: 1.0682x; 1.0353x over previous
//
#include <hip/hip_runtime.h>
#include <cstdint>
#include <cstddef>

// ---------------------------------------------------------------------------
// LSTM cell, B=8192, D=H=512, fp32 in/out.
// pre = [x|h] @ Wstack^T + bias ; gates -> c_t, h_t fused in GEMM epilogue.
// Round 3: 256x128 tile (grid 32x16 = 512 blocks = exactly 2/CU) to double
// arithmetic intensity per staged byte; wave tile back to 64x64 (4x4 frags).
// ---------------------------------------------------------------------------

typedef __attribute__((ext_vector_type(8))) short short8;   // 8 bf16 = 4 VGPRs
typedef __attribute__((ext_vector_type(4))) float floatx4;  // MFMA acc

#define AS1(p) ((const __attribute__((address_space(1))) void*)(p))
#define AS3(p) ((__attribute__((address_space(3))) void*)(p))

__device__ __forceinline__ unsigned short f2bf(float f) {
  union { float f; unsigned u; } v; v.f = f;
  unsigned u = v.u;
  return (unsigned short)((u + 0x7fffu + ((u >> 16) & 1u)) >> 16);  // RNE
}

// --------------------------- pack everything -------------------------------
// blocks [0,8192):   A[b][k] = k<512 ? x[b][k] : h[b][k-512]      (8192x1024)
// blocks [8192,10240): B[n][k], n=gate*512+hh (f,i,g,o), k<512 -> Wx else Wh
//                      plus bias[n] = bx+bh at k==0.
struct PackArgs {
  const float* x; const float* h;
  const float* wx[4]; const float* wh[4];
  const float* bx[4]; const float* bh[4];
  unsigned short* A; unsigned short* B; float* bias;
};

__global__ __launch_bounds__(256) void pack_all_kernel(PackArgs P) {
  const int bid = blockIdx.x;
  if (bid < 8192) {
    int e = (bid * 256 + threadIdx.x) * 4;
    int b = e >> 10, k = e & 1023;
    const float* src = (k < 512) ? (P.x + b * 512 + k)
                                 : (P.h + b * 512 + (k - 512));
    float4 v = *(const float4*)src;
    ushort4 o;
    o.x = f2bf(v.x); o.y = f2bf(v.y); o.z = f2bf(v.z); o.w = f2bf(v.w);
    *(ushort4*)(P.A + e) = o;
  } else {
    int e = ((bid - 8192) * 256 + threadIdx.x) * 4;
    int n = e >> 10, k = e & 1023;
    int g = n >> 9, hh = n & 511;
    const float* src = (k < 512) ? (P.wx[g] + hh * 512 + k)
                                 : (P.wh[g] + hh * 512 + (k - 512));
    float4 v = *(const float4*)src;
    ushort4 o;
    o.x = f2bf(v.x); o.y = f2bf(v.y); o.z = f2bf(v.z); o.w = f2bf(v.w);
    *(ushort4*)(P.B + e) = o;
    if (k == 0) P.bias[n] = P.bx[g][hh] + P.bh[g][hh];
  }
}

// --------------------------- fused GEMM + LSTM epilogue --------------------
// Grid (32,16): tile = 256 batch x (4 gates x 32 hidden). K=1024, BK=64.
// 512 threads = 8 waves; wave tile 64x64 (4x4 frags of 16x16x32 bf16).
// LDS: As 32KB @ [0,32768), Bs 16KB @ [32768,49152); epilogue overlays As.
__global__ __launch_bounds__(512, 4)
void lstm_gemm_kernel(const unsigned short* __restrict__ A,   // [8192][1024]
                      const unsigned short* __restrict__ B,   // [2048][1024]
                      const float* __restrict__ bias,         // [2048]
                      const float* __restrict__ c_prev,       // [8192][512]
                      float* __restrict__ h_out,              // [8192][512]
                      float* __restrict__ c_out) {            // [8192][512]
  __shared__ __align__(16) char smem[49152];
  __shared__ float biasS[128];

  const int tid  = threadIdx.x;
  const int lane = tid & 63;
  const int w    = tid >> 6;        // wave 0..7
  const int quad = lane >> 4;
  const int colA = lane & 15;
  const int m0   = blockIdx.x * 256;
  const int h0   = blockIdx.y * 32;

  if (tid < 128) {
    // ep-col c -> gate c>>5, hidden h0 + (c&31)
    biasS[tid] = bias[(tid >> 5) * 512 + h0 + (tid & 31)];
  }

  // staging: thread covers tile-row r = j*64 + (tid>>3), 16B chunk (tid&7);
  // global chunk XOR-swizzled by row&7 so ds_read_b128 frags are conflict-free
  const int srow = tid >> 3;        // 0..63
  const int cl   = tid & 7;
  const int cg   = cl ^ (srow & 7);

  floatx4 acc[4][4];
#pragma unroll
  for (int i = 0; i < 4; ++i)
#pragma unroll
    for (int j = 0; j < 4; ++j) acc[i][j] = (floatx4){0.f, 0.f, 0.f, 0.f};

  const int wm = (w >> 1) * 64;     // wave M offset in tile (0,64,128,192)
  const int wn = (w & 1) * 64;      // wave N' offset (N' = gate*32+h)

  const char* Ag = (const char*)A;
  const char* Bg = (const char*)B;

  for (int kt = 0; kt < 16; ++kt) {
    __syncthreads();                // prior LDS reads done
    const int kb = kt * 128;        // byte offset into 2048-B rows
#pragma unroll
    for (int j = 0; j < 4; ++j) {   // A: 256 rows
      int r = j * 64 + srow;        // tile row 0..255 (r&7 == srow&7)
      __builtin_amdgcn_global_load_lds(
          AS1(Ag + (size_t)(m0 + r) * 2048 + kb + cg * 16),
          AS3(smem + r * 128 + cl * 16), 16, 0, 0);
    }
#pragma unroll
    for (int j = 0; j < 2; ++j) {   // B: 128 rows (gate-major)
      int r = j * 64 + srow;        // tile row 0..127
      int grow = (r >> 5) * 512 + h0 + (r & 31);
      __builtin_amdgcn_global_load_lds(
          AS1(Bg + (size_t)grow * 2048 + kb + cg * 16),
          AS3(smem + 32768 + r * 128 + cl * 16), 16, 0, 0);
    }
    __syncthreads();                // drains vmcnt(0)

#pragma unroll
    for (int kk = 0; kk < 2; ++kk) {
      const int off = ((kk * 4 + quad) ^ (colA & 7)) * 16;
      short8 af[4], bfr[4];
#pragma unroll
      for (int mi = 0; mi < 4; ++mi)
        af[mi] = *(const short8*)(smem + (wm + mi * 16 + colA) * 128 + off);
#pragma unroll
      for (int ni = 0; ni < 4; ++ni)
        bfr[ni] = *(const short8*)(smem + 32768 + (wn + ni * 16 + colA) * 128 + off);
#pragma unroll
      for (int mi = 0; mi < 4; ++mi)
#pragma unroll
        for (int ni = 0; ni < 4; ++ni)
          acc[mi][ni] = __builtin_amdgcn_mfma_f32_16x16x32_bf16(
              af[mi], bfr[ni], acc[mi][ni], 0, 0, 0);
    }
  }

  // ------------------- fused epilogue (4 rounds of 64 M-rows) --------------
  __syncthreads();
  float* ep = (float*)smem;         // [64][132] padded, overlays As
#pragma unroll
  for (int rd = 0; rd < 4; ++rd) {
    if ((w >> 1) == rd) {           // the 2 waves with wm == rd*64
      // C/D layout: row = quad*4 + rr, col = lane&15
#pragma unroll
      for (int mi = 0; mi < 4; ++mi)
#pragma unroll
        for (int ni = 0; ni < 4; ++ni) {
          int rr0 = mi * 16 + quad * 4;                 // 0..63
          int cc  = wn + ni * 16 + colA;                // 0..127
#pragma unroll
          for (int rr = 0; rr < 4; ++rr)
            ep[(rr0 + rr) * 132 + cc] = acc[mi][ni][rr];
        }
    }
    __syncthreads();
#pragma unroll
    for (int j = 0; j < 4; ++j) {
      int idx  = j * 512 + tid;     // 0..2047
      int mloc = idx >> 5;
      int hh   = idx & 31;
      float pf = ep[mloc * 132 +      hh] + biasS[hh];
      float pi = ep[mloc * 132 + 32 + hh] + biasS[32 + hh];
      float pg = ep[mloc * 132 + 64 + hh] + biasS[64 + hh];
      float po = ep[mloc * 132 + 96 + hh] + biasS[96 + hh];
      float fg = 1.f / (1.f + __expf(-pf));
      float ig = 1.f / (1.f + __expf(-pi));
      float gg = 1.f - 2.f / (1.f + __expf(2.f * pg));
      float og = 1.f / (1.f + __expf(-po));
      int m  = m0 + rd * 64 + mloc;
      int hg = h0 + hh;
      float cp = c_prev[m * 512 + hg];
      float cv = fg * cp + ig * gg;
      float th = 1.f - 2.f / (1.f + __expf(2.f * cv));
      h_out[m * 512 + hg] = og * th;
      c_out[m * 512 + hg] = cv;
    }
    __syncthreads();
  }
}

// ---------------------------------------------------------------------------
extern "C" void kernel_launch(void* const* d_in, const int* in_sizes, int n_in,
                              void* d_out, int out_size, void* d_ws, size_t ws_size,
                              hipStream_t stream) {
  // workspace: A_bf16 (16 MiB) | B_bf16 (4 MiB) | bias (8 KiB)
  char* ws = (char*)d_ws;
  unsigned short* Abf = (unsigned short*)ws;
  unsigned short* Bbf = (unsigned short*)(ws + (size_t)16777216);
  float* bias = (float*)(ws + (size_t)16777216 + 4194304);

  float* hout = (float*)d_out;
  float* cout = hout + (size_t)8192 * 512;

  PackArgs P;
  P.x = (const float*)d_in[0];
  P.h = (const float*)d_in[1];
  // gate order in stacked B: 0=f, 1=i, 2=g(cell), 3=o
  P.wx[0] = (const float*)d_in[3];  P.bx[0] = (const float*)d_in[4];
  P.wh[0] = (const float*)d_in[5];  P.bh[0] = (const float*)d_in[6];
  P.wx[1] = (const float*)d_in[7];  P.bx[1] = (const float*)d_in[8];
  P.wh[1] = (const float*)d_in[9];  P.bh[1] = (const float*)d_in[10];
  P.wx[2] = (const float*)d_in[11]; P.bx[2] = (const float*)d_in[12];
  P.wh[2] = (const float*)d_in[13]; P.bh[2] = (const float*)d_in[14];
  P.wx[3] = (const float*)d_in[15]; P.bx[3] = (const float*)d_in[16];
  P.wh[3] = (const float*)d_in[17]; P.bh[3] = (const float*)d_in[18];
  P.A = Abf; P.B = Bbf; P.bias = bias;

  pack_all_kernel<<<10240, 256, 0, stream>>>(P);

  const float* c = (const float*)d_in[2];
  dim3 grid(32, 16);
  lstm_gemm_kernel<<<grid, 512, 0, stream>>>(Abf, Bbf, bias, c, hout, cout);
}